// Round 8
// baseline (2869.770 us; speedup 1.0000x reference)
//
#include <hip/hip_runtime.h>
#include <hip/hip_bf16.h>
#include <math.h>

#define DD    1024
#define SS    1024
#define BB    4
#define EE    4
#define DFF   4096
#define VOC   32000

typedef __attribute__((ext_vector_type(8))) short v8s;   // 8 bf16 (4 VGPRs)
typedef __attribute__((ext_vector_type(4))) float v4f;   // MFMA accumulator
typedef __attribute__((ext_vector_type(4))) float f32x4; // asm-friendly float4

// fp32 -> bf16 (RNE)
__device__ __forceinline__ unsigned short f2b(float f) {
    unsigned u = __float_as_uint(f);
    unsigned r = (u + 0x7FFFu + ((u >> 16) & 1u)) >> 16;
    return (unsigned short)r;
}
__device__ __forceinline__ float b2f(unsigned short h) {
    return __uint_as_float((unsigned)h << 16);
}

// bijective XCD-aware block swizzle (m204): safe for any nwg
__device__ __forceinline__ void xcd_swizzle(int& bx, int& by) {
    int gx = gridDim.x;
    int nwg = gx * gridDim.y;
    int id = by * gx + bx;
    int q = nwg >> 3, r = nwg & 7;
    int xcd = id & 7, o = id >> 3;
    int swz = (xcd < r ? xcd * (q + 1) : r * (q + 1) + (xcd - r) * q) + o;
    bx = swz % gx; by = swz / gx;
}

// ---------------------------------------------------------------------------
// split-bf16 casts for the U GEMM (Ootomo 3-term): x = hi + lo, both bf16.
// ---------------------------------------------------------------------------
template<bool GATHER>
__global__ __launch_bounds__(256)
void split_cast(const float* __restrict__ src, const int* __restrict__ tokens,
                unsigned short* __restrict__ Xhi, unsigned short* __restrict__ Xlo)
{
    const int row = blockIdx.x;
    const float4* s;
    if constexpr (GATHER)
        s = (const float4*)(src + (size_t)tokens[row] * DD);
    else
        s = (const float4*)(src + (size_t)row * DD);
    const int c = threadIdx.x;          // 256 float4 per 1024-wide row
    float4 v = s[c];
    ushort4 hi, lo;
    hi.x = f2b(v.x); hi.y = f2b(v.y); hi.z = f2b(v.z); hi.w = f2b(v.w);
    lo.x = f2b(v.x - b2f(hi.x)); lo.y = f2b(v.y - b2f(hi.y));
    lo.z = f2b(v.z - b2f(hi.z)); lo.w = f2b(v.w - b2f(hi.w));
    ((ushort4*)Xhi)[(size_t)row * 256 + c] = hi;
    ((ushort4*)Xlo)[(size_t)row * 256 + c] = lo;
}

// ---------------------------------------------------------------------------
// Persistent RNN v8: same wave-per-output layout as R7 (256 blocks x 1024
// threads, weights in 16 VGPRs via asm loads, launch_bounds(1024,4)).
// CHANGE: the publish lane (lane 0) no longer polls — its stores' vmcnt acks
// shared a counter with its poll, making it the per-step straggler that the
// block barrier waited on. Lane 1 now polls a 16B dwordx4 covering BOTH
// adjacent pairs (elements w*64 and w*64+1) and scatters both; lane 0 goes
// straight to the barrier after issuing its stores. Detection is carried
// exclusively by store-free threads.
// ---------------------------------------------------------------------------
__global__ __launch_bounds__(1024, 4)
void rnn_kernel(const float* __restrict__ U,
                const float* __restrict__ Whh,
                unsigned short* __restrict__ HSbf,
                unsigned long long* __restrict__ hpair,
                float* __restrict__ MEANX)
{
    __shared__ __align__(16) float hs_s[2][1280];   // h[k] at k + (k>>4)*4

    const int tid = threadIdx.x;
    const int b  = blockIdx.x >> 6;       // batch
    const int gg = blockIdx.x & 63;       // output group
    const int w  = tid >> 6;              // wave = output within group
    const int l  = tid & 63;              // lane = 16-float K slice
    const int d_own = gg * 16 + w;
    const bool is_res  = (l == 0);        // publisher (no polling)
    const bool is_dpol = (l == 1);        // double-poller (covers lane 0 too)

    // Whh[d_own][l*16 .. +16) in 4 VGPR quads, pinned via asm volatile loads
    const float* wrow = Whh + (size_t)d_own * DD + l * 16;
    f32x4 w0, w1, w2, w3;
    asm volatile("global_load_dwordx4 %0, %1, off"           : "=v"(w0) : "v"(wrow) : "memory");
    asm volatile("global_load_dwordx4 %0, %1, off offset:16" : "=v"(w1) : "v"(wrow) : "memory");
    asm volatile("global_load_dwordx4 %0, %1, off offset:32" : "=v"(w2) : "v"(wrow) : "memory");
    asm volatile("global_load_dwordx4 %0, %1, off offset:48" : "=v"(w3) : "v"(wrow) : "memory");
    asm volatile("s_waitcnt vmcnt(0)" ::: "memory");

    const int sofs  = tid + ((tid >> 4) << 2);    // scatter offset (skewed), own elem
    const int sofs2 = 80 * w;                     // lane1: elem w*64 position (and +1)
    const int rofs  = l * 20;                     // read base (skewed slice)
    unsigned long long* hp_b = hpair + (size_t)b * 2048;

    float m_acc = 0.f;

    for (int t = 0; t < SS; ++t) {
        const int par = t & 1;
        float u_pre = 0.f;
        if (is_res)
            u_pre = U[((size_t)(b * SS + t)) * DD + d_own];

        if (t > 0) {
            const unsigned tg = (unsigned)t;
            if (is_dpol) {
                // poll BOTH pairs (elements w*64, w*64+1) with one dwordx4
                const unsigned long long* pp =
                    hp_b + (size_t)((t - 1) & 1) * 1024 + (tid - 1);
                uint4 q;
                for (;;) {
                    asm volatile(
                        "global_load_dwordx4 %0, %1, off sc0 sc1\n\t"
                        "s_waitcnt vmcnt(0)"
                        : "=&v"(q) : "v"(pp) : "memory");
                    if ((q.y == tg) & (q.w == tg)) break;
                    __builtin_amdgcn_s_sleep(1);
                }
                *(float2*)&hs_s[par][sofs2] = make_float2(
                    __uint_as_float(q.x), __uint_as_float(q.z));
            } else if (!is_res) {
                // standard single-pair poll of own element
                const unsigned long long* pp =
                    hp_b + (size_t)((t - 1) & 1) * 1024 + tid;
                uint2 q;
                for (;;) {
                    asm volatile(
                        "global_load_dwordx2 %0, %1, off sc0 sc1\n\t"
                        "s_waitcnt vmcnt(0)"
                        : "=&v"(q) : "v"(pp) : "memory");
                    if (q.y == tg) break;
                    __builtin_amdgcn_s_sleep(1);
                }
                hs_s[par][sofs] = __uint_as_float(q.x);
            }
            // lane 0: no poll — straight to the barrier
        }
        __syncthreads();

        float acc = 0.f;
        if (t > 0) {
            const float* rb = &hs_s[par][rofs];
            f32x4 h0 = *(const f32x4*)(rb +  0);
            f32x4 h1 = *(const f32x4*)(rb +  4);
            f32x4 h2 = *(const f32x4*)(rb +  8);
            f32x4 h3 = *(const f32x4*)(rb + 12);
            acc  = w0.x*h0.x + w0.y*h0.y + w0.z*h0.z + w0.w*h0.w;
            acc += w1.x*h1.x + w1.y*h1.y + w1.z*h1.z + w1.w*h1.w;
            acc += w2.x*h2.x + w2.y*h2.y + w2.z*h2.z + w2.w*h2.w;
            acc += w3.x*h3.x + w3.y*h3.y + w3.z*h3.z + w3.w*h3.w;
            acc += __shfl_xor(acc, 1);
            acc += __shfl_xor(acc, 2);
            acc += __shfl_xor(acc, 4);
            acc += __shfl_xor(acc, 8);
            acc += __shfl_xor(acc, 16);
            acc += __shfl_xor(acc, 32);
        }

        if (is_res) {
            float h = tanhf(u_pre + acc);
            HSbf[((size_t)(b * SS + t)) * DD + d_own] = f2b(h);
            m_acc += h;
            unsigned long long pk =
                ((unsigned long long)(unsigned)(t + 1) << 32) |
                (unsigned long long)__float_as_uint(h);
            __hip_atomic_store(hp_b + (size_t)par * 1024 + d_own, pk,
                               __ATOMIC_RELAXED, __HIP_MEMORY_SCOPE_AGENT);
        }
    }

    if (is_res)
        MEANX[b * DD + d_own] = m_acc * (1.0f / (float)SS);
}

// gates = softmax(MEANX @ Wg^T); top-1 weight + index per batch. 1 block.
__global__ __launch_bounds__(256)
void gate_kernel(const float* __restrict__ MEANX, const float* __restrict__ Wg,
                 float* __restrict__ WGATE, int* __restrict__ IDX)
{
    __shared__ float sc[4][4];
    const int tid = threadIdx.x;
    const int p = tid >> 4, l = tid & 15;
    const int b = p >> 2, e = p & 3;
    float acc = 0.f;
    for (int j = 0; j < 64; ++j)
        acc += MEANX[b * DD + l * 64 + j] * Wg[e * DD + l * 64 + j];
    acc += __shfl_xor(acc, 1); acc += __shfl_xor(acc, 2);
    acc += __shfl_xor(acc, 4); acc += __shfl_xor(acc, 8);
    if (l == 0) sc[b][e] = acc;
    __syncthreads();
    if (tid < 4) {
        float s0 = sc[tid][0], s1 = sc[tid][1], s2 = sc[tid][2], s3 = sc[tid][3];
        float mx = fmaxf(fmaxf(s0, s1), fmaxf(s2, s3));
        float e0 = expf(s0 - mx), e1 = expf(s1 - mx);
        float e2 = expf(s2 - mx), e3 = expf(s3 - mx);
        float inv = 1.0f / (e0 + e1 + e2 + e3);
        float pr[4] = {e0 * inv, e1 * inv, e2 * inv, e3 * inv};
        int arg = 0; float best = pr[0];
        if (pr[1] > best) { best = pr[1]; arg = 1; }
        if (pr[2] > best) { best = pr[2]; arg = 2; }
        if (pr[3] > best) { best = pr[3]; arg = 3; }
        WGATE[tid] = best;
        IDX[tid] = arg;
    }
}

// fp32 -> bf16 cast, float4-granular, grid-stride
__global__ __launch_bounds__(256)
void cast_kernel(const float* __restrict__ in, unsigned short* __restrict__ out,
                 long long n4)
{
    long long stride = (long long)gridDim.x * blockDim.x;
    for (long long i = (long long)blockIdx.x * blockDim.x + threadIdx.x;
         i < n4; i += stride) {
        float4 v = ((const float4*)in)[i];
        ushort4 o;
        o.x = f2b(v.x); o.y = f2b(v.y); o.z = f2b(v.z); o.w = f2b(v.w);
        ((ushort4*)out)[i] = o;
    }
}

// transpose-cast: src fp32 [R][C] (expert expIdx[z]) -> dst bf16 [C][R] (z)
__global__ __launch_bounds__(256)
void transpose_cast(const float* __restrict__ src, const int* __restrict__ expIdx,
                    unsigned short* __restrict__ dst, int R, int C,
                    long long srcExpStride, long long dstZStride)
{
    __shared__ float tbuf[32][33];
    const int tid = threadIdx.x;
    const int z = blockIdx.z;
    const float* S = src + (long long)expIdx[z] * srcExpStride;
    unsigned short* D = dst + (long long)z * dstZStride;
    const int r0 = blockIdx.y * 32, c0 = blockIdx.x * 32;
    const int tr = tid >> 3, tc = (tid & 7) * 4;
    float4 v = *(const float4*)(S + (long long)(r0 + tr) * C + c0 + tc);
    tbuf[tr][tc + 0] = v.x; tbuf[tr][tc + 1] = v.y;
    tbuf[tr][tc + 2] = v.z; tbuf[tr][tc + 3] = v.w;
    __syncthreads();
    ushort4 o;
    o.x = f2b(tbuf[tc + 0][tr]); o.y = f2b(tbuf[tc + 1][tr]);
    o.z = f2b(tbuf[tc + 2][tr]); o.w = f2b(tbuf[tc + 3][tr]);
    *(ushort4*)(D + (long long)(c0 + tr) * R + r0 + tc) = o;
}

// ---------------------------------------------------------------------------
// bf16 MFMA GEMM (m97 structure): C = A[M][K] @ Bt[N][K]^T, fused epilogues.
// EPI 0: +bias -> fp32 | EPI 1: gelu(x+bias[e]) -> bf16 | EPI 2: (x+bias[e])*w -> bf16
// ---------------------------------------------------------------------------
__device__ __forceinline__ void load_lds16(const void* g, void* l) {
    __builtin_amdgcn_global_load_lds(
        (const __attribute__((address_space(1))) unsigned int*)g,
        (__attribute__((address_space(3))) unsigned int*)l, 16, 0, 0);
}

template<int EPI>
__global__ __launch_bounds__(256)
void gemm_bf16(const unsigned short* __restrict__ A,
               const unsigned short* __restrict__ Bt,
               const float* __restrict__ bias,
               void* __restrict__ Cv,
               int N, int K,
               long long aStride, long long cStride, long long btStride,
               const float* __restrict__ scaleP, const int* __restrict__ expIdx)
{
    __shared__ __align__(16) unsigned short Asm[128 * 32];
    __shared__ __align__(16) unsigned short Bsm[128 * 32];

    const int tid = threadIdx.x;
    const int wave = tid >> 6, lane = tid & 63;
    int bxs = blockIdx.x, bys = blockIdx.y;
    xcd_swizzle(bxs, bys);
    const int bm = bys * 128, bn = bxs * 128;
    const int bz = blockIdx.z;
    const int wm = (wave >> 1) * 64, wn = (wave & 1) * 64;
    const int fr = lane & 15, kh = lane >> 4;

    const unsigned short* Az  = A  + (long long)bz * aStride;
    const unsigned short* Btz = Bt + (long long)bz * btStride;
    const float* bp = bias + (expIdx ? (long long)expIdx[bz] * N : 0);

    const int lo0 = wave * 1024 + lane * 16;
    const int lo1 = 4096 + lo0;
    const int r0 = lo0 >> 6, q0 = (lo0 & 63) >> 1;
    const int r1 = lo1 >> 6, q1 = (lo1 & 63) >> 1;
    const unsigned short* a0 = Az  + (size_t)(bm + r0) * K + q0;
    const unsigned short* a1 = Az  + (size_t)(bm + r1) * K + q1;
    const unsigned short* b0 = Btz + (size_t)(bn + r0) * K + q0;
    const unsigned short* b1 = Btz + (size_t)(bn + r1) * K + q1;

    v4f acc[4][4];
    #pragma unroll
    for (int i = 0; i < 4; ++i)
        #pragma unroll
        for (int j = 0; j < 4; ++j) {
            acc[i][j][0] = 0.f; acc[i][j][1] = 0.f;
            acc[i][j][2] = 0.f; acc[i][j][3] = 0.f;
        }

    for (int k0 = 0; k0 < K; k0 += 32) {
        load_lds16(a0 + k0, (char*)Asm + wave * 1024);
        load_lds16(a1 + k0, (char*)Asm + 4096 + wave * 1024);
        load_lds16(b0 + k0, (char*)Bsm + wave * 1024);
        load_lds16(b1 + k0, (char*)Bsm + 4096 + wave * 1024);
        __syncthreads();

        v8s af[4], bfv[4];
        #pragma unroll
        for (int f = 0; f < 4; ++f) {
            af[f]  = *(const v8s*)((const char*)Asm + ((wm + f * 16 + fr) << 6) + (kh << 4));
            bfv[f] = *(const v8s*)((const char*)Bsm + ((wn + f * 16 + fr) << 6) + (kh << 4));
        }
        #pragma unroll
        for (int fi = 0; fi < 4; ++fi)
            #pragma unroll
            for (int fj = 0; fj < 4; ++fj)
                acc[fi][fj] = __builtin_amdgcn_mfma_f32_16x16x32_bf16(
                    af[fi], bfv[fj], acc[fi][fj], 0, 0, 0);
        __syncthreads();
    }

    const float scale = (EPI == 2) ? scaleP[bz] : 1.0f;
    #pragma unroll
    for (int fi = 0; fi < 4; ++fi) {
        #pragma unroll
        for (int fj = 0; fj < 4; ++fj) {
            v4f t = acc[fi][fj];
            int col = bn + wn + fj * 16 + fr;
            float bb = bp[col];
            int rbase = bm + wm + fi * 16 + (kh << 2);
            #pragma unroll
            for (int r = 0; r < 4; ++r) {
                float v = t[r] + bb;
                if constexpr (EPI == 1)
                    v = 0.5f * v * (1.0f + erff(v * 0.70710678118654752440f));
                if constexpr (EPI == 2)
                    v *= scale;
                size_t off = (size_t)bz * (size_t)cStride +
                             (size_t)(rbase + r) * N + col;
                if constexpr (EPI == 0)
                    ((float*)Cv)[off] = v;
                else
                    ((unsigned short*)Cv)[off] = f2b(v);
            }
        }
    }
}

// ---------------------------------------------------------------------------
// split-bf16 MFMA GEMM for U: C = Ahi@Bhi^T + Ahi@Blo^T + Alo@Bhi^T
//                                + bias1 + bias2  (fp32 out, ~fp32 accuracy)
// ---------------------------------------------------------------------------
__global__ __launch_bounds__(256)
void gemm_bf16_split(const unsigned short* __restrict__ Ahi,
                     const unsigned short* __restrict__ Alo,
                     const unsigned short* __restrict__ Bhi,
                     const unsigned short* __restrict__ Blo,
                     const float* __restrict__ bias1,
                     const float* __restrict__ bias2,
                     float* __restrict__ C, int N, int K)
{
    __shared__ __align__(16) unsigned short AsmH[128 * 32];
    __shared__ __align__(16) unsigned short AsmL[128 * 32];
    __shared__ __align__(16) unsigned short BsmH[128 * 32];
    __shared__ __align__(16) unsigned short BsmL[128 * 32];

    const int tid = threadIdx.x;
    const int wave = tid >> 6, lane = tid & 63;
    int bxs = blockIdx.x, bys = blockIdx.y;
    xcd_swizzle(bxs, bys);
    const int bm = bys * 128, bn = bxs * 128;
    const int wm = (wave >> 1) * 64, wn = (wave & 1) * 64;
    const int fr = lane & 15, kh = lane >> 4;

    const int lo0 = wave * 1024 + lane * 16;
    const int lo1 = 4096 + lo0;
    const int r0 = lo0 >> 6, q0 = (lo0 & 63) >> 1;
    const int r1 = lo1 >> 6, q1 = (lo1 & 63) >> 1;
    const unsigned short* ah0 = Ahi + (size_t)(bm + r0) * K + q0;
    const unsigned short* ah1 = Ahi + (size_t)(bm + r1) * K + q1;
    const unsigned short* al0 = Alo + (size_t)(bm + r0) * K + q0;
    const unsigned short* al1 = Alo + (size_t)(bm + r1) * K + q1;
    const unsigned short* bh0 = Bhi + (size_t)(bn + r0) * K + q0;
    const unsigned short* bh1 = Bhi + (size_t)(bn + r1) * K + q1;
    const unsigned short* bl0 = Blo + (size_t)(bn + r0) * K + q0;
    const unsigned short* bl1 = Blo + (size_t)(bn + r1) * K + q1;

    v4f acc[4][4];
    #pragma unroll
    for (int i = 0; i < 4; ++i)
        #pragma unroll
        for (int j = 0; j < 4; ++j) {
            acc[i][j][0] = 0.f; acc[i][j][1] = 0.f;
            acc[i][j][2] = 0.f; acc[i][j][3] = 0.f;
        }

    for (int k0 = 0; k0 < K; k0 += 32) {
        load_lds16(ah0 + k0, (char*)AsmH + wave * 1024);
        load_lds16(ah1 + k0, (char*)AsmH + 4096 + wave * 1024);
        load_lds16(al0 + k0, (char*)AsmL + wave * 1024);
        load_lds16(al1 + k0, (char*)AsmL + 4096 + wave * 1024);
        load_lds16(bh0 + k0, (char*)BsmH + wave * 1024);
        load_lds16(bh1 + k0, (char*)BsmH + 4096 + wave * 1024);
        load_lds16(bl0 + k0, (char*)BsmL + wave * 1024);
        load_lds16(bl1 + k0, (char*)BsmL + 4096 + wave * 1024);
        __syncthreads();

        v8s ahf[4], alf[4];
        #pragma unroll
        for (int f = 0; f < 4; ++f) {
            int ao = ((wm + f * 16 + fr) << 6) + (kh << 4);
            ahf[f] = *(const v8s*)((const char*)AsmH + ao);
            alf[f] = *(const v8s*)((const char*)AsmL + ao);
        }
        #pragma unroll
        for (int fj = 0; fj < 4; ++fj) {
            int bo = ((wn + fj * 16 + fr) << 6) + (kh << 4);
            v8s bh = *(const v8s*)((const char*)BsmH + bo);
            v8s bl = *(const v8s*)((const char*)BsmL + bo);
            #pragma unroll
            for (int fi = 0; fi < 4; ++fi) {
                acc[fi][fj] = __builtin_amdgcn_mfma_f32_16x16x32_bf16(
                    alf[fi], bh, acc[fi][fj], 0, 0, 0);
                acc[fi][fj] = __builtin_amdgcn_mfma_f32_16x16x32_bf16(
                    ahf[fi], bl, acc[fi][fj], 0, 0, 0);
                acc[fi][fj] = __builtin_amdgcn_mfma_f32_16x16x32_bf16(
                    ahf[fi], bh, acc[fi][fj], 0, 0, 0);
            }
        }
        __syncthreads();
    }

    #pragma unroll
    for (int fi = 0; fi < 4; ++fi) {
        #pragma unroll
        for (int fj = 0; fj < 4; ++fj) {
            v4f t = acc[fi][fj];
            int col = bn + wn + fj * 16 + fr;
            float bb = bias1[col] + bias2[col];
            int rbase = bm + wm + fi * 16 + (kh << 2);
            #pragma unroll
            for (int r = 0; r < 4; ++r)
                C[(size_t)(rbase + r) * N + col] = t[r] + bb;
        }
    }
}

// ---------------------------------------------------------------------------
extern "C" void kernel_launch(void* const* d_in, const int* in_sizes, int n_in,
                              void* d_out, int out_size, void* d_ws, size_t ws_size,
                              hipStream_t stream)
{
    const int*   tokens = (const int*)  d_in[0];
    const float* emb    = (const float*)d_in[1];
    const float* Wih    = (const float*)d_in[2];
    const float* bih    = (const float*)d_in[3];
    const float* Whh    = (const float*)d_in[4];
    const float* bhh    = (const float*)d_in[5];
    const float* Wg     = (const float*)d_in[6];
    const float* W1     = (const float*)d_in[7];
    const float* b1     = (const float*)d_in[8];
    const float* W2     = (const float*)d_in[9];
    const float* b2     = (const float*)d_in[10];
    const float* Wfc    = (const float*)d_in[11];
    const float* bfc    = (const float*)d_in[12];
    float* out = (float*)d_out;
    float* ws  = (float*)d_ws;

    // ws layout (float offsets), ~117.4 MB, aliased by lifetime:
    float*          U     = ws;                                   // 4,194,304 fl
    float*          HSdead= ws + 4194304;                         // recycled
    unsigned short* HSbf  = (unsigned short*)(ws + 8388608);      // 2,097,152 fl
    float*          Ebase = ws + 10485760;                        // 8,388,608 fl (32MB)
    float*          Fbase = ws + 18874368;                        // 8,388,608 fl (32MB)
    unsigned short* Ybf   = (unsigned short*)(ws + 27262976);     // 2,097,152 fl
    float*          MEANX = ws + 29360128;                        // 4096
    float*          WGATE = ws + 29364224;                        // 4
    int*            IDX   = (int*)(ws + 29364228);                // 4
    // aliases (lifetimes disjoint in stream order):
    unsigned long long* HPAIR = (unsigned long long*)HSdead;      // 64 KB (BB*2*1024 pairs)
    unsigned short* Xhi   = (unsigned short*)Ebase;               // 8MB, pre-RNN
    unsigned short* Xlo   = (unsigned short*)(Ebase + 2097152);   // 8MB, pre-RNN
    unsigned short* Whi   = (unsigned short*)(Ebase + 4194304);   // 2MB, pre-RNN
    unsigned short* Wlo   = (unsigned short*)(Ebase + 4718592);   // 2MB, pre-RNN
    unsigned short* W1T   = (unsigned short*)Ebase;               // 32MB, post-gate
    unsigned short* W2T   = (unsigned short*)Ebase;               // 32MB
    unsigned short* H1bf  = (unsigned short*)Fbase;               // 32MB
    unsigned short* Wfcbf = (unsigned short*)Ebase;               // 62.5MB spans E+F

    hipMemsetAsync(HPAIR, 0, (size_t)BB * 2 * 1024 * sizeof(unsigned long long),
                   stream);

    // split-bf16 casts: X = emb[tokens], W = Wih (N x K for A@B^T)
    split_cast<true ><<<BB * SS, 256, 0, stream>>>(emb, tokens, Xhi, Xlo);
    split_cast<false><<<DD, 256, 0, stream>>>(Wih, nullptr, Whi, Wlo);

    // U = X @ Wih^T + bih + bhh  (3-term split-bf16 MFMA, ~fp32-exact)
    gemm_bf16_split<<<dim3(DD / 128, (BB * SS) / 128, 1), 256, 0, stream>>>(
        Xhi, Xlo, Whi, Wlo, bih, bhh, U, DD, DD);

    // RNN scan (v8: publish lanes freed from polling; produces HSbf + MEANX)
    rnn_kernel<<<256, 1024, 0, stream>>>(U, Whh, HSbf, HPAIR, MEANX);

    // gate (fp32 path)
    gate_kernel<<<1, 256, 0, stream>>>(MEANX, Wg, WGATE, IDX);

    // W1T[z] = bf16(W1[idx[z]]^T)  [DFF][DD]   (clobbers Xhi/Xlo/Whi/Wlo: dead)
    transpose_cast<<<dim3(DFF / 32, DD / 32, BB), 256, 0, stream>>>(
        W1, IDX, W1T, DD, DFF, (long long)DD * DFF, (long long)DFF * DD);

    // H1bf = gelu(HSbf @ W1T^T + b1[e])  (bf16 out)
    gemm_bf16<1><<<dim3(DFF / 128, SS / 128, BB), 256, 0, stream>>>(
        HSbf, W1T, b1, H1bf, DFF, DD,
        (long long)SS * DD, (long long)SS * DFF, (long long)DFF * DD,
        nullptr, IDX);

    // W2T[z] = bf16(W2[idx[z]]^T)  [DD][DFF]   (clobbers W1T: dead)
    transpose_cast<<<dim3(DD / 32, DFF / 32, BB), 256, 0, stream>>>(
        W2, IDX, W2T, DFF, DD, (long long)DFF * DD, (long long)DD * DFF);

    // Ybf = (H1bf @ W2T^T + b2[e]) * w  (bf16 out)
    gemm_bf16<2><<<dim3(DD / 128, SS / 128, BB), 256, 0, stream>>>(
        H1bf, W2T, b2, Ybf, DD, DFF,
        (long long)SS * DFF, (long long)SS * DD, (long long)DD * DFF,
        WGATE, IDX);

    // Wfc -> bf16 (clobbers W2T + H1bf: dead)
    cast_kernel<<<4096, 256, 0, stream>>>(Wfc, Wfcbf, (long long)VOC * DD / 4);

    // logits = Ybf @ Wfcbf^T + bfc  (fp32 out)
    gemm_bf16<0><<<dim3(VOC / 128, (BB * SS) / 128, 1), 256, 0, stream>>>(
        Ybf, Wfcbf, bfc, out, VOC, DD, 0, 0, 0, nullptr, nullptr);
}

// Round 9
// 2769.389 us; speedup vs baseline: 1.0362x; 1.0362x over previous
//
#include <hip/hip_runtime.h>
#include <hip/hip_bf16.h>
#include <math.h>

#define DD    1024
#define SS    1024
#define BB    4
#define EE    4
#define DFF   4096
#define VOC   32000

typedef __attribute__((ext_vector_type(8))) short v8s;   // 8 bf16 (4 VGPRs)
typedef __attribute__((ext_vector_type(4))) float v4f;   // MFMA accumulator
typedef __attribute__((ext_vector_type(4))) float f32x4; // asm-friendly float4

// fp32 -> bf16 (RNE)
__device__ __forceinline__ unsigned short f2b(float f) {
    unsigned u = __float_as_uint(f);
    unsigned r = (u + 0x7FFFu + ((u >> 16) & 1u)) >> 16;
    return (unsigned short)r;
}
__device__ __forceinline__ float b2f(unsigned short h) {
    return __uint_as_float((unsigned)h << 16);
}

// bijective XCD-aware block swizzle (m204): safe for any nwg
__device__ __forceinline__ void xcd_swizzle(int& bx, int& by) {
    int gx = gridDim.x;
    int nwg = gx * gridDim.y;
    int id = by * gx + bx;
    int q = nwg >> 3, r = nwg & 7;
    int xcd = id & 7, o = id >> 3;
    int swz = (xcd < r ? xcd * (q + 1) : r * (q + 1) + (xcd - r) * q) + o;
    bx = swz % gx; by = swz / gx;
}

// ---------------------------------------------------------------------------
// split-bf16 casts for the U GEMM (Ootomo 3-term): x = hi + lo, both bf16.
// ---------------------------------------------------------------------------
template<bool GATHER>
__global__ __launch_bounds__(256)
void split_cast(const float* __restrict__ src, const int* __restrict__ tokens,
                unsigned short* __restrict__ Xhi, unsigned short* __restrict__ Xlo)
{
    const int row = blockIdx.x;
    const float4* s;
    if constexpr (GATHER)
        s = (const float4*)(src + (size_t)tokens[row] * DD);
    else
        s = (const float4*)(src + (size_t)row * DD);
    const int c = threadIdx.x;          // 256 float4 per 1024-wide row
    float4 v = s[c];
    ushort4 hi, lo;
    hi.x = f2b(v.x); hi.y = f2b(v.y); hi.z = f2b(v.z); hi.w = f2b(v.w);
    lo.x = f2b(v.x - b2f(hi.x)); lo.y = f2b(v.y - b2f(hi.y));
    lo.z = f2b(v.z - b2f(hi.z)); lo.w = f2b(v.w - b2f(hi.w));
    ((ushort4*)Xhi)[(size_t)row * 256 + c] = hi;
    ((ushort4*)Xlo)[(size_t)row * 256 + c] = lo;
}

// ---------------------------------------------------------------------------
// Persistent RNN (R7 configuration — best measured, 2.07-2.13 us/step):
// 256 blocks x 1024 threads, __launch_bounds__(1024,4) (128-VGPR cap so the
// 16 weight VGPRs stay resident; asm loads pin them). Block (b = blk>>6,
// gg = blk&63) owns outputs [gg*16, gg*16+16) of batch b; wave w computes
// output gg*16+w; lane l holds Whh[d][l*16..+16).
// Tagged-pair sync: hpair[b][parity][1024] (val, step+1); poll = one 8B
// dwordx2 sc0 sc1 per thread; single barrier/step (parity double-buffer:
// barrier(t) separates scatter(t) from read(t); reaching scatter(t+2)
// implies passing barrier(t+1), so all reads of buf[par] are done).
// Six protocol variants (R2-R8) all land at 2.0-2.25 us/step: this is the
// agent-scope exchange latency floor, not a tunable.
// ---------------------------------------------------------------------------
__global__ __launch_bounds__(1024, 4)
void rnn_kernel(const float* __restrict__ U,
                const float* __restrict__ Whh,
                unsigned short* __restrict__ HSbf,
                unsigned long long* __restrict__ hpair,
                float* __restrict__ MEANX)
{
    __shared__ __align__(16) float hs_s[2][1280];   // h[k] at k + (k>>4)*4

    const int tid = threadIdx.x;
    const int b  = blockIdx.x >> 6;       // batch
    const int gg = blockIdx.x & 63;       // output group
    const int w  = tid >> 6;              // wave = output within group
    const int l  = tid & 63;              // lane = 16-float K slice
    const int d_own = gg * 16 + w;
    const bool is_res = (l == 0);

    // Whh[d_own][l*16 .. +16) in 4 VGPR quads, pinned via asm volatile loads
    const float* wrow = Whh + (size_t)d_own * DD + l * 16;
    f32x4 w0, w1, w2, w3;
    asm volatile("global_load_dwordx4 %0, %1, off"           : "=v"(w0) : "v"(wrow) : "memory");
    asm volatile("global_load_dwordx4 %0, %1, off offset:16" : "=v"(w1) : "v"(wrow) : "memory");
    asm volatile("global_load_dwordx4 %0, %1, off offset:32" : "=v"(w2) : "v"(wrow) : "memory");
    asm volatile("global_load_dwordx4 %0, %1, off offset:48" : "=v"(w3) : "v"(wrow) : "memory");
    asm volatile("s_waitcnt vmcnt(0)" ::: "memory");

    const int sofs = tid + ((tid >> 4) << 2);     // scatter offset (skewed)
    const int rofs = l * 20;                      // read base (skewed slice)
    unsigned long long* hp_b = hpair + (size_t)b * 2048;

    float m_acc = 0.f;

    for (int t = 0; t < SS; ++t) {
        const int par = t & 1;
        float u_pre = 0.f;
        if (is_res)
            u_pre = U[((size_t)(b * SS + t)) * DD + d_own];

        if (t > 0) {
            const unsigned long long* pp = hp_b + (size_t)((t - 1) & 1) * 1024 + tid;
            uint2 q;
            const unsigned tg = (unsigned)t;
            for (;;) {
                asm volatile(
                    "global_load_dwordx2 %0, %1, off sc0 sc1\n\t"
                    "s_waitcnt vmcnt(0)"
                    : "=&v"(q) : "v"(pp) : "memory");
                if (q.y == tg) break;
                __builtin_amdgcn_s_sleep(1);
            }
            hs_s[par][sofs] = __uint_as_float(q.x);
        }
        __syncthreads();

        float acc = 0.f;
        if (t > 0) {
            const float* rb = &hs_s[par][rofs];
            f32x4 h0 = *(const f32x4*)(rb +  0);
            f32x4 h1 = *(const f32x4*)(rb +  4);
            f32x4 h2 = *(const f32x4*)(rb +  8);
            f32x4 h3 = *(const f32x4*)(rb + 12);
            acc  = w0.x*h0.x + w0.y*h0.y + w0.z*h0.z + w0.w*h0.w;
            acc += w1.x*h1.x + w1.y*h1.y + w1.z*h1.z + w1.w*h1.w;
            acc += w2.x*h2.x + w2.y*h2.y + w2.z*h2.z + w2.w*h2.w;
            acc += w3.x*h3.x + w3.y*h3.y + w3.z*h3.z + w3.w*h3.w;
            acc += __shfl_xor(acc, 1);
            acc += __shfl_xor(acc, 2);
            acc += __shfl_xor(acc, 4);
            acc += __shfl_xor(acc, 8);
            acc += __shfl_xor(acc, 16);
            acc += __shfl_xor(acc, 32);
        }

        if (is_res) {
            float h = tanhf(u_pre + acc);
            HSbf[((size_t)(b * SS + t)) * DD + d_own] = f2b(h);
            m_acc += h;
            unsigned long long pk =
                ((unsigned long long)(unsigned)(t + 1) << 32) |
                (unsigned long long)__float_as_uint(h);
            __hip_atomic_store(hp_b + (size_t)par * 1024 + d_own, pk,
                               __ATOMIC_RELAXED, __HIP_MEMORY_SCOPE_AGENT);
        }
    }

    if (is_res)
        MEANX[b * DD + d_own] = m_acc * (1.0f / (float)SS);
}

// gates = softmax(MEANX @ Wg^T); top-1 weight + index per batch. 1 block.
__global__ __launch_bounds__(256)
void gate_kernel(const float* __restrict__ MEANX, const float* __restrict__ Wg,
                 float* __restrict__ WGATE, int* __restrict__ IDX)
{
    __shared__ float sc[4][4];
    const int tid = threadIdx.x;
    const int p = tid >> 4, l = tid & 15;
    const int b = p >> 2, e = p & 3;
    float acc = 0.f;
    for (int j = 0; j < 64; ++j)
        acc += MEANX[b * DD + l * 64 + j] * Wg[e * DD + l * 64 + j];
    acc += __shfl_xor(acc, 1); acc += __shfl_xor(acc, 2);
    acc += __shfl_xor(acc, 4); acc += __shfl_xor(acc, 8);
    if (l == 0) sc[b][e] = acc;
    __syncthreads();
    if (tid < 4) {
        float s0 = sc[tid][0], s1 = sc[tid][1], s2 = sc[tid][2], s3 = sc[tid][3];
        float mx = fmaxf(fmaxf(s0, s1), fmaxf(s2, s3));
        float e0 = expf(s0 - mx), e1 = expf(s1 - mx);
        float e2 = expf(s2 - mx), e3 = expf(s3 - mx);
        float inv = 1.0f / (e0 + e1 + e2 + e3);
        float pr[4] = {e0 * inv, e1 * inv, e2 * inv, e3 * inv};
        int arg = 0; float best = pr[0];
        if (pr[1] > best) { best = pr[1]; arg = 1; }
        if (pr[2] > best) { best = pr[2]; arg = 2; }
        if (pr[3] > best) { best = pr[3]; arg = 3; }
        WGATE[tid] = best;
        IDX[tid] = arg;
    }
}

// fp32 -> bf16 cast, float4-granular, grid-stride
__global__ __launch_bounds__(256)
void cast_kernel(const float* __restrict__ in, unsigned short* __restrict__ out,
                 long long n4)
{
    long long stride = (long long)gridDim.x * blockDim.x;
    for (long long i = (long long)blockIdx.x * blockDim.x + threadIdx.x;
         i < n4; i += stride) {
        float4 v = ((const float4*)in)[i];
        ushort4 o;
        o.x = f2b(v.x); o.y = f2b(v.y); o.z = f2b(v.z); o.w = f2b(v.w);
        ((ushort4*)out)[i] = o;
    }
}

// transpose-cast: src fp32 [R][C] (expert expIdx[z]) -> dst bf16 [C][R] (z)
__global__ __launch_bounds__(256)
void transpose_cast(const float* __restrict__ src, const int* __restrict__ expIdx,
                    unsigned short* __restrict__ dst, int R, int C,
                    long long srcExpStride, long long dstZStride)
{
    __shared__ float tbuf[32][33];
    const int tid = threadIdx.x;
    const int z = blockIdx.z;
    const float* S = src + (long long)expIdx[z] * srcExpStride;
    unsigned short* D = dst + (long long)z * dstZStride;
    const int r0 = blockIdx.y * 32, c0 = blockIdx.x * 32;
    const int tr = tid >> 3, tc = (tid & 7) * 4;
    float4 v = *(const float4*)(S + (long long)(r0 + tr) * C + c0 + tc);
    tbuf[tr][tc + 0] = v.x; tbuf[tr][tc + 1] = v.y;
    tbuf[tr][tc + 2] = v.z; tbuf[tr][tc + 3] = v.w;
    __syncthreads();
    ushort4 o;
    o.x = f2b(tbuf[tc + 0][tr]); o.y = f2b(tbuf[tc + 1][tr]);
    o.z = f2b(tbuf[tc + 2][tr]); o.w = f2b(tbuf[tc + 3][tr]);
    *(ushort4*)(D + (long long)(c0 + tr) * R + r0 + tc) = o;
}

// ---------------------------------------------------------------------------
// bf16 MFMA GEMM (m97 structure): C = A[M][K] @ Bt[N][K]^T, fused epilogues.
// EPI 0: +bias -> fp32 | EPI 1: gelu(x+bias[e]) -> bf16 | EPI 2: (x+bias[e])*w -> bf16
// ---------------------------------------------------------------------------
__device__ __forceinline__ void load_lds16(const void* g, void* l) {
    __builtin_amdgcn_global_load_lds(
        (const __attribute__((address_space(1))) unsigned int*)g,
        (__attribute__((address_space(3))) unsigned int*)l, 16, 0, 0);
}

template<int EPI>
__global__ __launch_bounds__(256)
void gemm_bf16(const unsigned short* __restrict__ A,
               const unsigned short* __restrict__ Bt,
               const float* __restrict__ bias,
               void* __restrict__ Cv,
               int N, int K,
               long long aStride, long long cStride, long long btStride,
               const float* __restrict__ scaleP, const int* __restrict__ expIdx)
{
    __shared__ __align__(16) unsigned short Asm[128 * 32];
    __shared__ __align__(16) unsigned short Bsm[128 * 32];

    const int tid = threadIdx.x;
    const int wave = tid >> 6, lane = tid & 63;
    int bxs = blockIdx.x, bys = blockIdx.y;
    xcd_swizzle(bxs, bys);
    const int bm = bys * 128, bn = bxs * 128;
    const int bz = blockIdx.z;
    const int wm = (wave >> 1) * 64, wn = (wave & 1) * 64;
    const int fr = lane & 15, kh = lane >> 4;

    const unsigned short* Az  = A  + (long long)bz * aStride;
    const unsigned short* Btz = Bt + (long long)bz * btStride;
    const float* bp = bias + (expIdx ? (long long)expIdx[bz] * N : 0);

    const int lo0 = wave * 1024 + lane * 16;
    const int lo1 = 4096 + lo0;
    const int r0 = lo0 >> 6, q0 = (lo0 & 63) >> 1;
    const int r1 = lo1 >> 6, q1 = (lo1 & 63) >> 1;
    const unsigned short* a0 = Az  + (size_t)(bm + r0) * K + q0;
    const unsigned short* a1 = Az  + (size_t)(bm + r1) * K + q1;
    const unsigned short* b0 = Btz + (size_t)(bn + r0) * K + q0;
    const unsigned short* b1 = Btz + (size_t)(bn + r1) * K + q1;

    v4f acc[4][4];
    #pragma unroll
    for (int i = 0; i < 4; ++i)
        #pragma unroll
        for (int j = 0; j < 4; ++j) {
            acc[i][j][0] = 0.f; acc[i][j][1] = 0.f;
            acc[i][j][2] = 0.f; acc[i][j][3] = 0.f;
        }

    for (int k0 = 0; k0 < K; k0 += 32) {
        load_lds16(a0 + k0, (char*)Asm + wave * 1024);
        load_lds16(a1 + k0, (char*)Asm + 4096 + wave * 1024);
        load_lds16(b0 + k0, (char*)Bsm + wave * 1024);
        load_lds16(b1 + k0, (char*)Bsm + 4096 + wave * 1024);
        __syncthreads();

        v8s af[4], bfv[4];
        #pragma unroll
        for (int f = 0; f < 4; ++f) {
            af[f]  = *(const v8s*)((const char*)Asm + ((wm + f * 16 + fr) << 6) + (kh << 4));
            bfv[f] = *(const v8s*)((const char*)Bsm + ((wn + f * 16 + fr) << 6) + (kh << 4));
        }
        #pragma unroll
        for (int fi = 0; fi < 4; ++fi)
            #pragma unroll
            for (int fj = 0; fj < 4; ++fj)
                acc[fi][fj] = __builtin_amdgcn_mfma_f32_16x16x32_bf16(
                    af[fi], bfv[fj], acc[fi][fj], 0, 0, 0);
        __syncthreads();
    }

    const float scale = (EPI == 2) ? scaleP[bz] : 1.0f;
    #pragma unroll
    for (int fi = 0; fi < 4; ++fi) {
        #pragma unroll
        for (int fj = 0; fj < 4; ++fj) {
            v4f t = acc[fi][fj];
            int col = bn + wn + fj * 16 + fr;
            float bb = bp[col];
            int rbase = bm + wm + fi * 16 + (kh << 2);
            #pragma unroll
            for (int r = 0; r < 4; ++r) {
                float v = t[r] + bb;
                if constexpr (EPI == 1)
                    v = 0.5f * v * (1.0f + erff(v * 0.70710678118654752440f));
                if constexpr (EPI == 2)
                    v *= scale;
                size_t off = (size_t)bz * (size_t)cStride +
                             (size_t)(rbase + r) * N + col;
                if constexpr (EPI == 0)
                    ((float*)Cv)[off] = v;
                else
                    ((unsigned short*)Cv)[off] = f2b(v);
            }
        }
    }
}

// ---------------------------------------------------------------------------
// split-bf16 MFMA GEMM for U: C = Ahi@Bhi^T + Ahi@Blo^T + Alo@Bhi^T
//                                + bias1 + bias2  (fp32 out, ~fp32 accuracy)
// ---------------------------------------------------------------------------
__global__ __launch_bounds__(256)
void gemm_bf16_split(const unsigned short* __restrict__ Ahi,
                     const unsigned short* __restrict__ Alo,
                     const unsigned short* __restrict__ Bhi,
                     const unsigned short* __restrict__ Blo,
                     const float* __restrict__ bias1,
                     const float* __restrict__ bias2,
                     float* __restrict__ C, int N, int K)
{
    __shared__ __align__(16) unsigned short AsmH[128 * 32];
    __shared__ __align__(16) unsigned short AsmL[128 * 32];
    __shared__ __align__(16) unsigned short BsmH[128 * 32];
    __shared__ __align__(16) unsigned short BsmL[128 * 32];

    const int tid = threadIdx.x;
    const int wave = tid >> 6, lane = tid & 63;
    int bxs = blockIdx.x, bys = blockIdx.y;
    xcd_swizzle(bxs, bys);
    const int bm = bys * 128, bn = bxs * 128;
    const int wm = (wave >> 1) * 64, wn = (wave & 1) * 64;
    const int fr = lane & 15, kh = lane >> 4;

    const int lo0 = wave * 1024 + lane * 16;
    const int lo1 = 4096 + lo0;
    const int r0 = lo0 >> 6, q0 = (lo0 & 63) >> 1;
    const int r1 = lo1 >> 6, q1 = (lo1 & 63) >> 1;
    const unsigned short* ah0 = Ahi + (size_t)(bm + r0) * K + q0;
    const unsigned short* ah1 = Ahi + (size_t)(bm + r1) * K + q1;
    const unsigned short* al0 = Alo + (size_t)(bm + r0) * K + q0;
    const unsigned short* al1 = Alo + (size_t)(bm + r1) * K + q1;
    const unsigned short* bh0 = Bhi + (size_t)(bn + r0) * K + q0;
    const unsigned short* bh1 = Bhi + (size_t)(bn + r1) * K + q1;
    const unsigned short* bl0 = Blo + (size_t)(bn + r0) * K + q0;
    const unsigned short* bl1 = Blo + (size_t)(bn + r1) * K + q1;

    v4f acc[4][4];
    #pragma unroll
    for (int i = 0; i < 4; ++i)
        #pragma unroll
        for (int j = 0; j < 4; ++j) {
            acc[i][j][0] = 0.f; acc[i][j][1] = 0.f;
            acc[i][j][2] = 0.f; acc[i][j][3] = 0.f;
        }

    for (int k0 = 0; k0 < K; k0 += 32) {
        load_lds16(ah0 + k0, (char*)AsmH + wave * 1024);
        load_lds16(ah1 + k0, (char*)AsmH + 4096 + wave * 1024);
        load_lds16(al0 + k0, (char*)AsmL + wave * 1024);
        load_lds16(al1 + k0, (char*)AsmL + 4096 + wave * 1024);
        load_lds16(bh0 + k0, (char*)BsmH + wave * 1024);
        load_lds16(bh1 + k0, (char*)BsmH + 4096 + wave * 1024);
        load_lds16(bl0 + k0, (char*)BsmL + wave * 1024);
        load_lds16(bl1 + k0, (char*)BsmL + 4096 + wave * 1024);
        __syncthreads();

        v8s ahf[4], alf[4];
        #pragma unroll
        for (int f = 0; f < 4; ++f) {
            int ao = ((wm + f * 16 + fr) << 6) + (kh << 4);
            ahf[f] = *(const v8s*)((const char*)AsmH + ao);
            alf[f] = *(const v8s*)((const char*)AsmL + ao);
        }
        #pragma unroll
        for (int fj = 0; fj < 4; ++fj) {
            int bo = ((wn + fj * 16 + fr) << 6) + (kh << 4);
            v8s bh = *(const v8s*)((const char*)BsmH + bo);
            v8s bl = *(const v8s*)((const char*)BsmL + bo);
            #pragma unroll
            for (int fi = 0; fi < 4; ++fi) {
                acc[fi][fj] = __builtin_amdgcn_mfma_f32_16x16x32_bf16(
                    alf[fi], bh, acc[fi][fj], 0, 0, 0);
                acc[fi][fj] = __builtin_amdgcn_mfma_f32_16x16x32_bf16(
                    ahf[fi], bl, acc[fi][fj], 0, 0, 0);
                acc[fi][fj] = __builtin_amdgcn_mfma_f32_16x16x32_bf16(
                    ahf[fi], bh, acc[fi][fj], 0, 0, 0);
            }
        }
        __syncthreads();
    }

    #pragma unroll
    for (int fi = 0; fi < 4; ++fi) {
        #pragma unroll
        for (int fj = 0; fj < 4; ++fj) {
            v4f t = acc[fi][fj];
            int col = bn + wn + fj * 16 + fr;
            float bb = bias1[col] + bias2[col];
            int rbase = bm + wm + fi * 16 + (kh << 2);
            #pragma unroll
            for (int r = 0; r < 4; ++r)
                C[(size_t)(rbase + r) * N + col] = t[r] + bb;
        }
    }
}

// ---------------------------------------------------------------------------
extern "C" void kernel_launch(void* const* d_in, const int* in_sizes, int n_in,
                              void* d_out, int out_size, void* d_ws, size_t ws_size,
                              hipStream_t stream)
{
    const int*   tokens = (const int*)  d_in[0];
    const float* emb    = (const float*)d_in[1];
    const float* Wih    = (const float*)d_in[2];
    const float* bih    = (const float*)d_in[3];
    const float* Whh    = (const float*)d_in[4];
    const float* bhh    = (const float*)d_in[5];
    const float* Wg     = (const float*)d_in[6];
    const float* W1     = (const float*)d_in[7];
    const float* b1     = (const float*)d_in[8];
    const float* W2     = (const float*)d_in[9];
    const float* b2     = (const float*)d_in[10];
    const float* Wfc    = (const float*)d_in[11];
    const float* bfc    = (const float*)d_in[12];
    float* out = (float*)d_out;
    float* ws  = (float*)d_ws;

    // ws layout (float offsets), ~117.4 MB, aliased by lifetime:
    float*          U     = ws;                                   // 4,194,304 fl
    float*          HSdead= ws + 4194304;                         // recycled
    unsigned short* HSbf  = (unsigned short*)(ws + 8388608);      // 2,097,152 fl
    float*          Ebase = ws + 10485760;                        // 8,388,608 fl (32MB)
    float*          Fbase = ws + 18874368;                        // 8,388,608 fl (32MB)
    unsigned short* Ybf   = (unsigned short*)(ws + 27262976);     // 2,097,152 fl
    float*          MEANX = ws + 29360128;                        // 4096
    float*          WGATE = ws + 29364224;                        // 4
    int*            IDX   = (int*)(ws + 29364228);                // 4
    // aliases (lifetimes disjoint in stream order):
    unsigned long long* HPAIR = (unsigned long long*)HSdead;      // 64 KB (BB*2*1024 pairs)
    unsigned short* Xhi   = (unsigned short*)Ebase;               // 8MB, pre-RNN
    unsigned short* Xlo   = (unsigned short*)(Ebase + 2097152);   // 8MB, pre-RNN
    unsigned short* Whi   = (unsigned short*)(Ebase + 4194304);   // 2MB, pre-RNN
    unsigned short* Wlo   = (unsigned short*)(Ebase + 4718592);   // 2MB, pre-RNN
    unsigned short* W1T   = (unsigned short*)Ebase;               // 32MB, post-gate
    unsigned short* W2T   = (unsigned short*)Ebase;               // 32MB
    unsigned short* H1bf  = (unsigned short*)Fbase;               // 32MB
    unsigned short* Wfcbf = (unsigned short*)Ebase;               // 62.5MB spans E+F

    hipMemsetAsync(HPAIR, 0, (size_t)BB * 2 * 1024 * sizeof(unsigned long long),
                   stream);

    // split-bf16 casts: X = emb[tokens], W = Wih (N x K for A@B^T)
    split_cast<true ><<<BB * SS, 256, 0, stream>>>(emb, tokens, Xhi, Xlo);
    split_cast<false><<<DD, 256, 0, stream>>>(Wih, nullptr, Whi, Wlo);

    // U = X @ Wih^T + bih + bhh  (3-term split-bf16 MFMA, ~fp32-exact)
    gemm_bf16_split<<<dim3(DD / 128, (BB * SS) / 128, 1), 256, 0, stream>>>(
        Xhi, Xlo, Whi, Wlo, bih, bhh, U, DD, DD);

    // RNN scan (R7 config: wave-per-output, tagged-pair sync)
    rnn_kernel<<<256, 1024, 0, stream>>>(U, Whh, HSbf, HPAIR, MEANX);

    // gate (fp32 path)
    gate_kernel<<<1, 256, 0, stream>>>(MEANX, Wg, WGATE, IDX);

    // W1T[z] = bf16(W1[idx[z]]^T)  [DFF][DD]   (clobbers Xhi/Xlo/Whi/Wlo: dead)
    transpose_cast<<<dim3(DFF / 32, DD / 32, BB), 256, 0, stream>>>(
        W1, IDX, W1T, DD, DFF, (long long)DD * DFF, (long long)DFF * DD);

    // H1bf = gelu(HSbf @ W1T^T + b1[e])  (bf16 out)
    gemm_bf16<1><<<dim3(DFF / 128, SS / 128, BB), 256, 0, stream>>>(
        HSbf, W1T, b1, H1bf, DFF, DD,
        (long long)SS * DD, (long long)SS * DFF, (long long)DFF * DD,
        nullptr, IDX);

    // W2T[z] = bf16(W2[idx[z]]^T)  [DD][DFF]   (clobbers W1T: dead)
    transpose_cast<<<dim3(DD / 32, DFF / 32, BB), 256, 0, stream>>>(
        W2, IDX, W2T, DFF, DD, (long long)DFF * DD, (long long)DD * DFF);

    // Ybf = (H1bf @ W2T^T + b2[e]) * w  (bf16 out)
    gemm_bf16<2><<<dim3(DD / 128, SS / 128, BB), 256, 0, stream>>>(
        H1bf, W2T, b2, Ybf, DD, DFF,
        (long long)SS * DFF, (long long)SS * DD, (long long)DD * DFF,
        WGATE, IDX);

    // Wfc -> bf16 (clobbers W2T + H1bf: dead)
    cast_kernel<<<4096, 256, 0, stream>>>(Wfc, Wfcbf, (long long)VOC * DD / 4);

    // logits = Ybf @ Wfcbf^T + bfc  (fp32 out)
    gemm_bf16<0><<<dim3(VOC / 128, (BB * SS) / 128, 1), 256, 0, stream>>>(
        Ybf, Wfcbf, bfc, out, VOC, DD, 0, 0, 0, nullptr, nullptr);
}